// Round 3
// baseline (486.591 us; speedup 1.0000x reference)
//
#include <hip/hip_runtime.h>

#define NROWS 16384
#define KCB   16384
#define DD    64
#define BM    256
#define CSPLIT 16
#define COLS_PER_BLOCK (KCB / CSPLIT)            // 1024
#define STAGE_COLS 128
#define NSTAGES (COLS_PER_BLOCK / STAGE_COLS)    // 8
#define NCHUNK (STAGE_COLS / 32)                 // 4
#define CAP 4096
#define DELTA 0.9f

typedef __attribute__((ext_vector_type(8))) short bf16x8;
typedef __attribute__((ext_vector_type(4))) float f32x4;

__device__ __forceinline__ unsigned pk_bf16(float lo, float hi) {
    unsigned a = __float_as_uint(lo);
    unsigned b = __float_as_uint(hi);
    a += 0x7FFFu + ((a >> 16) & 1u);   // RNE to bf16
    b += 0x7FFFu + ((b >> 16) & 1u);
    return (a >> 16) | (b & 0xFFFF0000u);
}

__device__ __forceinline__ bf16x8 mk8(unsigned a, unsigned b, unsigned c, unsigned d) {
    union { uint4 u; bf16x8 v; } x;
    x.u = make_uint4(a, b, c, d);
    return x.v;
}

// XOR swizzle within 128B rows: bank-conflict-free b128 reads/writes
__device__ __forceinline__ unsigned swz(unsigned row, unsigned byte_in_row) {
    return row * 128u + (byte_in_row ^ ((row & 7u) << 4));
}

template<int PASS>
__global__ __launch_bounds__(512, 2) void score_kernel(
    const float* __restrict__ x_re, const float* __restrict__ x_im,
    const float* __restrict__ cb_re, const float* __restrict__ cb_im,
    unsigned* __restrict__ row_max_bits,
    unsigned long long* __restrict__ best_packed)
{
    __shared__ char Bls[2][3][STAGE_COLS * 128];   // 96 KB: [buf][t1/t2/t3 operand][col][d bf16]
    __shared__ unsigned cand[CAP];                 // 16 KB
    __shared__ int cand_cnt;

    const int tid  = threadIdx.x;
    const int lane = tid & 63;
    const int wid  = tid >> 6;          // 0..7
    const int row0 = blockIdx.x * BM;
    const int col0 = blockIdx.y * COLS_PER_BLOCK;
    const int wr0  = (wid >> 1) * 64;   // 4 row-groups of 64
    const int wcg  = wid & 1;           // 2 col-groups of 16
    const int l15  = lane & 15;
    const int lhi  = lane >> 4;         // 0..3

    if (tid == 0) cand_cnt = 0;

    // ---- A fragments: built once, held in registers (no LDS, no re-reads) ----
    bf16x8 Ar[4][2], Ai[4][2], Ad[4][2];
#pragma unroll
    for (int a = 0; a < 4; ++a) {
        const int row = row0 + wr0 + a * 16 + l15;
#pragma unroll
        for (int ks = 0; ks < 2; ++ks) {
            const float4* pr = (const float4*)(x_re + (size_t)row * DD + ks * 32 + lhi * 8);
            const float4* pi = (const float4*)(x_im + (size_t)row * DD + ks * 32 + lhi * 8);
            float4 r0 = pr[0], r1 = pr[1];
            float4 i0 = pi[0], i1 = pi[1];
            Ar[a][ks] = mk8(pk_bf16(r0.x, r0.y), pk_bf16(r0.z, r0.w),
                            pk_bf16(r1.x, r1.y), pk_bf16(r1.z, r1.w));
            Ai[a][ks] = mk8(pk_bf16(i0.x, i0.y), pk_bf16(i0.z, i0.w),
                            pk_bf16(i1.x, i1.y), pk_bf16(i1.z, i1.w));
            Ad[a][ks] = mk8(pk_bf16(r0.x - i0.x, r0.y - i0.y),
                            pk_bf16(r0.z - i0.z, r0.w - i0.w),
                            pk_bf16(r1.x - i1.x, r1.y - i1.y),
                            pk_bf16(r1.z - i1.z, r1.w - i1.w));
        }
    }

    // per-lane running max (pass1) / filter thresholds (pass2)
    float rm[4][4];
    float thr[4][4];
#pragma unroll
    for (int a = 0; a < 4; ++a)
#pragma unroll
        for (int r = 0; r < 4; ++r) rm[a][r] = 0.0f;
    if (PASS == 2) {
#pragma unroll
        for (int a = 0; a < 4; ++a)
#pragma unroll
            for (int r = 0; r < 4; ++r) {
                int n = row0 + wr0 + a * 16 + lhi * 4 + r;
                float mx = __uint_as_float(row_max_bits[n]);
                float tm = sqrtf(mx) - DELTA;
                thr[a][r] = (tm > 0.0f) ? tm * tm : -1.0f;
            }
    }

    // ---- B staging: 128 cols/stage, reg-staged (issue-early / write-late) ----
    const int sc  = tid >> 2;          // 0..127 col within stage
    const int sd0 = (tid & 3) * 16;    // d offset (16 floats per thread)
    float4 rr[4], ri[4];

    auto stage_load = [&](int s) {
        const size_t base = (size_t)(col0 + s * STAGE_COLS + sc) * DD + sd0;
        const float4* gr = (const float4*)(cb_re + base);
        const float4* gi = (const float4*)(cb_im + base);
#pragma unroll
        for (int j = 0; j < 4; ++j) { rr[j] = gr[j]; ri[j] = gi[j]; }
    };
    auto stage_write = [&](int buf) {
        char* br = Bls[buf][0];
        char* bi = Bls[buf][1];
        char* bs = Bls[buf][2];
#pragma unroll
        for (int h = 0; h < 2; ++h) {
            float4 a0 = rr[2 * h], a1 = rr[2 * h + 1];
            float4 b0 = ri[2 * h], b1 = ri[2 * h + 1];
            unsigned off = swz(sc, sd0 * 2 + h * 16);
            *(uint4*)(br + off) = make_uint4(
                pk_bf16(a0.x, a0.y), pk_bf16(a0.z, a0.w),
                pk_bf16(a1.x, a1.y), pk_bf16(a1.z, a1.w));
            *(uint4*)(bi + off) = make_uint4(
                pk_bf16(b0.x, b0.y), pk_bf16(b0.z, b0.w),
                pk_bf16(b1.x, b1.y), pk_bf16(b1.z, b1.w));
            *(uint4*)(bs + off) = make_uint4(
                pk_bf16(a0.x + b0.x, a0.y + b0.y), pk_bf16(a0.z + b0.z, a0.w + b0.w),
                pk_bf16(a1.x + b1.x, a1.y + b1.y), pk_bf16(a1.z + b1.z, a1.w + b1.w));
        }
    };

    stage_load(0);
    stage_write(0);
    __syncthreads();

    for (int s = 0; s < NSTAGES; ++s) {
        const int cur = s & 1;
        if (s + 1 < NSTAGES) stage_load(s + 1);   // HBM latency hides under MFMA

        const char* B1 = Bls[cur][0];
        const char* B2 = Bls[cur][1];
        const char* B3 = Bls[cur][2];

        for (int ch = 0; ch < NCHUNK; ++ch) {
            const int colLocal = ch * 32 + wcg * 16 + l15;

            f32x4 t1[4], t2[4], t3[4];
#pragma unroll
            for (int a = 0; a < 4; ++a) {
                t1[a] = (f32x4){0.f, 0.f, 0.f, 0.f};
                t2[a] = (f32x4){0.f, 0.f, 0.f, 0.f};
                t3[a] = (f32x4){0.f, 0.f, 0.f, 0.f};
            }

#pragma unroll
            for (int ks = 0; ks < 2; ++ks) {
                unsigned off = swz(colLocal, ks * 64 + lhi * 16);
                bf16x8 b1 = *(const bf16x8*)(B1 + off);
                bf16x8 b2 = *(const bf16x8*)(B2 + off);
                bf16x8 b3 = *(const bf16x8*)(B3 + off);
#pragma unroll
                for (int a = 0; a < 4; ++a) {
                    t1[a] = __builtin_amdgcn_mfma_f32_16x16x32_bf16(Ar[a][ks], b1, t1[a], 0, 0, 0);
                    t2[a] = __builtin_amdgcn_mfma_f32_16x16x32_bf16(Ai[a][ks], b2, t2[a], 0, 0, 0);
                    t3[a] = __builtin_amdgcn_mfma_f32_16x16x32_bf16(Ad[a][ks], b3, t3[a], 0, 0, 0);
                }
            }

            // epilogue: Re = t1+t2, Im = t3-t1+t2
#pragma unroll
            for (int a = 0; a < 4; ++a)
#pragma unroll
                for (int r = 0; r < 4; ++r) {
                    float v1 = t1[a][r], v2 = t2[a][r], v3 = t3[a][r];
                    float re = v1 + v2;
                    float im = (v3 - v1) + v2;
                    float m2 = fmaf(re, re, im * im);
                    if (PASS == 1) {
                        rm[a][r] = fmaxf(rm[a][r], m2);
                    } else {
                        if (m2 >= thr[a][r]) {
                            int n = row0 + wr0 + a * 16 + lhi * 4 + r;
                            int k = col0 + s * STAGE_COLS + ch * 32 + wcg * 16 + l15;
                            int idx = atomicAdd(&cand_cnt, 1);
                            if (idx < CAP) cand[idx] = ((unsigned)n << 14) | (unsigned)k;
                        }
                    }
                }
        }

        if (s + 1 < NSTAGES) stage_write(1 - cur);
        __syncthreads();
    }

    if (PASS == 1) {
        // reduce per-row max across the 16 column lanes, then global atomicMax
#pragma unroll
        for (int m = 1; m < 16; m <<= 1)
#pragma unroll
            for (int a = 0; a < 4; ++a)
#pragma unroll
                for (int r = 0; r < 4; ++r)
                    rm[a][r] = fmaxf(rm[a][r], __shfl_xor(rm[a][r], m, 64));
        if (l15 == 0) {
#pragma unroll
            for (int a = 0; a < 4; ++a)
#pragma unroll
                for (int r = 0; r < 4; ++r) {
                    int n = row0 + wr0 + a * 16 + lhi * 4 + r;
                    atomicMax(&row_max_bits[n], __float_as_uint(rm[a][r]));
                }
        }
    } else {
        // exact fp32 rescore of surviving candidates (round-1 FMA order -> absmax 0)
        int cnt = cand_cnt < CAP ? cand_cnt : CAP;
        for (int i = tid; i < cnt; i += 512) {
            unsigned e = cand[i];
            int n = (int)(e >> 14);
            int k = (int)(e & 16383u);
            const float* xr = x_re + (size_t)n * DD;
            const float* xi = x_im + (size_t)n * DD;
            const float* cr = cb_re + (size_t)k * DD;
            const float* ci = cb_im + (size_t)k * DD;
            float accr = 0.0f, acci = 0.0f;
            for (int d = 0; d < DD; ++d) {
                float xrv = xr[d], xiv = xi[d], crv = cr[d], civ = ci[d];
                accr = fmaf(xrv, crv, accr);
                accr = fmaf(xiv, civ, accr);
                acci = fmaf(xrv, civ, acci);
                acci = fmaf(-xiv, crv, acci);
            }
            float m2 = accr * accr + acci * acci;
            unsigned long long key =
                ((unsigned long long)__float_as_uint(m2) << 32) | (unsigned)(~(unsigned)k);
            atomicMax(&best_packed[n], key);
        }
    }
}

__global__ __launch_bounds__(256) void init_ws(unsigned* row_max_bits,
                                               unsigned long long* best_packed)
{
    int i = blockIdx.x * 256 + threadIdx.x;
    if (i < NROWS) { row_max_bits[i] = 0u; best_packed[i] = 0ull; }
}

__global__ __launch_bounds__(256) void finalize(
    const unsigned long long* __restrict__ best_packed,
    const float* __restrict__ cb_re, const float* __restrict__ cb_im,
    float* __restrict__ out)
{
    const int wave = threadIdx.x >> 6;
    const int lane = threadIdx.x & 63;
    const int n = blockIdx.x * 4 + wave;
    if (n >= NROWS) return;

    unsigned long long p = best_packed[n];
    unsigned k = ~(unsigned)(p & 0xFFFFFFFFull);

    if (lane == 0) out[n] = (float)k;

    float re = cb_re[(size_t)k * DD + lane];
    float im = cb_im[(size_t)k * DD + lane];
    float2* ro = reinterpret_cast<float2*>(out + NROWS);
    ro[(size_t)n * DD + lane] = make_float2(re, im);
}

extern "C" void kernel_launch(void* const* d_in, const int* in_sizes, int n_in,
                              void* d_out, int out_size, void* d_ws, size_t ws_size,
                              hipStream_t stream)
{
    const float* x_re  = (const float*)d_in[0];
    const float* x_im  = (const float*)d_in[1];
    const float* cb_re = (const float*)d_in[2];
    const float* cb_im = (const float*)d_in[3];
    float* out = (float*)d_out;

    unsigned* row_max_bits = (unsigned*)d_ws;                            // 64 KB
    unsigned long long* best_packed =
        (unsigned long long*)((char*)d_ws + sizeof(unsigned) * NROWS);   // 128 KB

    init_ws<<<NROWS / 256, 256, 0, stream>>>(row_max_bits, best_packed);

    dim3 grid(NROWS / BM, CSPLIT);
    score_kernel<1><<<grid, 512, 0, stream>>>(x_re, x_im, cb_re, cb_im,
                                              row_max_bits, best_packed);
    score_kernel<2><<<grid, 512, 0, stream>>>(x_re, x_im, cb_re, cb_im,
                                              row_max_bits, best_packed);

    finalize<<<NROWS / 4, 256, 0, stream>>>(best_packed, cb_re, cb_im, out);
}

// Round 4
// 335.843 us; speedup vs baseline: 1.4489x; 1.4489x over previous
//
#include <hip/hip_runtime.h>

#define NROWS 16384
#define KCB   16384
#define DD    64
#define BM    256
#define CSPLIT 16
#define COLS_PER_BLOCK 1024
#define TILE_COLS 128
#define NTILES (COLS_PER_BLOCK / TILE_COLS)   // 8
#define NCHUNK (TILE_COLS / 16)               // 8
#define CAP 2048
#define DELTA 0.45f

typedef __attribute__((ext_vector_type(8))) short bf16x8;
typedef __attribute__((ext_vector_type(4))) float f32x4;

__device__ __forceinline__ unsigned pk_bf16(float lo, float hi) {
    unsigned a = __float_as_uint(lo);
    unsigned b = __float_as_uint(hi);
    a += 0x7FFFu + ((a >> 16) & 1u);   // RNE to bf16
    b += 0x7FFFu + ((b >> 16) & 1u);
    return (a >> 16) | (b & 0xFFFF0000u);
}

__device__ __forceinline__ bf16x8 mk8(unsigned a, unsigned b, unsigned c, unsigned d) {
    union { uint4 u; bf16x8 v; } x;
    x.u = make_uint4(a, b, c, d);
    return x.v;
}

// XOR swizzle within 128B rows: 2-way max aliasing on 16-lane b128 groups (free)
__device__ __forceinline__ unsigned swz(unsigned row, unsigned byte_in_row) {
    return row * 128u + (byte_in_row ^ ((row & 7u) << 4));
}

// prep: zero reductions; optionally convert codebook fp32 -> bf16 (linear [k][64])
__global__ __launch_bounds__(256) void prep(
    const float* __restrict__ cb_re, const float* __restrict__ cb_im,
    uint4* __restrict__ cbr_ws, uint4* __restrict__ cbi_ws,
    unsigned* __restrict__ row_max_bits, unsigned long long* __restrict__ best_packed,
    int do_conv)
{
    int id = blockIdx.x * 256 + threadIdx.x;
    if (id < NROWS) { row_max_bits[id] = 0u; best_packed[id] = 0ull; }
    if (!do_conv) return;
    // 262144 threads: row = id>>4, sub = id&15 -> {arr, d0}
    int row = id >> 4;
    int sub = id & 15;
    const float* src = (sub >> 3) ? cb_im : cb_re;
    uint4* dst = (sub >> 3) ? cbi_ws : cbr_ws;
    int d0 = (sub & 7) * 8;
    const float4* p = (const float4*)(src + (size_t)row * DD + d0);
    float4 f0 = p[0], f1 = p[1];
    dst[row * 8 + (sub & 7)] = make_uint4(
        pk_bf16(f0.x, f0.y), pk_bf16(f0.z, f0.w),
        pk_bf16(f1.x, f1.y), pk_bf16(f1.z, f1.w));
}

template<int PASS, bool PRE>
__global__ __launch_bounds__(512, 4) void score_kernel(
    const float* __restrict__ x_re, const float* __restrict__ x_im,
    const float* __restrict__ cb_re, const float* __restrict__ cb_im,
    const uint4* __restrict__ cbr_ws, const uint4* __restrict__ cbi_ws,
    unsigned* __restrict__ row_max_bits,
    unsigned long long* __restrict__ best_packed)
{
    __shared__ char Bls[2][2][TILE_COLS * 128];   // 64 KB: [buf][re/im][col][d bf16 swz]
    __shared__ unsigned cand[CAP];                // 8 KB
    __shared__ int cand_cnt;

    const int tid  = threadIdx.x;
    const int lane = tid & 63;
    const int wid  = tid >> 6;          // 0..7 = row-group of 32
    const int row0 = blockIdx.x * BM;
    const int col0 = blockIdx.y * COLS_PER_BLOCK;
    const int l15  = lane & 15;
    const int lhi  = lane >> 4;         // 0..3

    if (tid == 0) cand_cnt = 0;

    // ---- A fragments: 32 rows/wave, re+im, built once in registers (32 VGPR) ----
    bf16x8 Ar[2][2], Ai[2][2];
#pragma unroll
    for (int a = 0; a < 2; ++a) {
        const int row = row0 + wid * 32 + a * 16 + l15;
#pragma unroll
        for (int ks = 0; ks < 2; ++ks) {
            const float4* pr = (const float4*)(x_re + (size_t)row * DD + ks * 32 + lhi * 8);
            const float4* pi = (const float4*)(x_im + (size_t)row * DD + ks * 32 + lhi * 8);
            float4 r0 = pr[0], r1 = pr[1];
            float4 i0 = pi[0], i1 = pi[1];
            Ar[a][ks] = mk8(pk_bf16(r0.x, r0.y), pk_bf16(r0.z, r0.w),
                            pk_bf16(r1.x, r1.y), pk_bf16(r1.z, r1.w));
            Ai[a][ks] = mk8(pk_bf16(i0.x, i0.y), pk_bf16(i0.z, i0.w),
                            pk_bf16(i1.x, i1.y), pk_bf16(i1.z, i1.w));
        }
    }

    float rm[2][4];
    float thr[2][4];
#pragma unroll
    for (int a = 0; a < 2; ++a)
#pragma unroll
        for (int r = 0; r < 4; ++r) rm[a][r] = 0.0f;
    if (PASS == 2) {
#pragma unroll
        for (int a = 0; a < 2; ++a)
#pragma unroll
            for (int r = 0; r < 4; ++r) {
                int n = row0 + wid * 32 + a * 16 + lhi * 4 + r;
                float mx = __uint_as_float(row_max_bits[n]);
                float tm = sqrtf(mx) - DELTA;
                thr[a][r] = (tm > 0.0f) ? tm * tm : -1.0f;
            }
    }

    // ---- B staging: per tile 128 cols x 128B x {re,im}; thread owns 32B per array ----
    const int scol  = tid >> 2;           // 0..127
    const int sboff = (tid & 3) * 32;     // byte offset within 128B row
    uint4 g[4];                           // in-flight staged regs (16 VGPR)

    auto stage_load = [&](int t) {
        if (PRE) {
            const size_t base = (size_t)(col0 + t * TILE_COLS) * 8 + tid * 2;  // uint4 units
            g[0] = cbr_ws[base];     g[1] = cbr_ws[base + 1];
            g[2] = cbi_ws[base];     g[3] = cbi_ws[base + 1];
        } else {
            const int col = col0 + t * TILE_COLS + scol;
            const int d0  = (tid & 3) * 16;
            const float4* pr = (const float4*)(cb_re + (size_t)col * DD + d0);
            const float4* pi = (const float4*)(cb_im + (size_t)col * DD + d0);
            float4 a0 = pr[0], a1 = pr[1], a2 = pr[2], a3 = pr[3];
            float4 b0 = pi[0], b1 = pi[1], b2 = pi[2], b3 = pi[3];
            g[0] = make_uint4(pk_bf16(a0.x,a0.y), pk_bf16(a0.z,a0.w), pk_bf16(a1.x,a1.y), pk_bf16(a1.z,a1.w));
            g[1] = make_uint4(pk_bf16(a2.x,a2.y), pk_bf16(a2.z,a2.w), pk_bf16(a3.x,a3.y), pk_bf16(a3.z,a3.w));
            g[2] = make_uint4(pk_bf16(b0.x,b0.y), pk_bf16(b0.z,b0.w), pk_bf16(b1.x,b1.y), pk_bf16(b1.z,b1.w));
            g[3] = make_uint4(pk_bf16(b2.x,b2.y), pk_bf16(b2.z,b2.w), pk_bf16(b3.x,b3.y), pk_bf16(b3.z,b3.w));
        }
    };
    auto stage_write = [&](int buf) {
        unsigned o0 = swz(scol, sboff);
        unsigned o1 = swz(scol, sboff + 16);
        *(uint4*)(&Bls[buf][0][0] + o0) = g[0];
        *(uint4*)(&Bls[buf][0][0] + o1) = g[1];
        *(uint4*)(&Bls[buf][1][0] + o0) = g[2];
        *(uint4*)(&Bls[buf][1][0] + o1) = g[3];
    };

    stage_load(0);
    stage_write(0);
    __syncthreads();

    for (int t = 0; t < NTILES; ++t) {
        const int cur = t & 1;
        if (t + 1 < NTILES) stage_load(t + 1);   // HBM/L2 latency hides under MFMA

        const char* B0 = &Bls[cur][0][0];
        const char* B1 = &Bls[cur][1][0];

        for (int ch = 0; ch < NCHUNK; ++ch) {
            const int colLocal = ch * 16 + l15;

            f32x4 accre[2], accim[2];
#pragma unroll
            for (int a = 0; a < 2; ++a) {
                accre[a] = (f32x4){0.f, 0.f, 0.f, 0.f};
                accim[a] = (f32x4){0.f, 0.f, 0.f, 0.f};
            }

#pragma unroll
            for (int ks = 0; ks < 2; ++ks) {
                unsigned off = swz(colLocal, ks * 64 + lhi * 16);
                bf16x8 br = *(const bf16x8*)(B0 + off);
                bf16x8 bi = *(const bf16x8*)(B1 + off);
#pragma unroll
                for (int a = 0; a < 2; ++a)
                    accre[a] = __builtin_amdgcn_mfma_f32_16x16x32_bf16(Ar[a][ks], br, accre[a], 0, 0, 0);
#pragma unroll
                for (int a = 0; a < 2; ++a)
                    accre[a] = __builtin_amdgcn_mfma_f32_16x16x32_bf16(Ai[a][ks], bi, accre[a], 0, 0, 0);
#pragma unroll
                for (int a = 0; a < 2; ++a)
                    accim[a] = __builtin_amdgcn_mfma_f32_16x16x32_bf16(Ar[a][ks], bi, accim[a], 0, 0, 0);
                br = br ^ (short)0x8000;   // -c_re, in-register, zero extra VGPRs
#pragma unroll
                for (int a = 0; a < 2; ++a)
                    accim[a] = __builtin_amdgcn_mfma_f32_16x16x32_bf16(Ai[a][ks], br, accim[a], 0, 0, 0);
            }

#pragma unroll
            for (int a = 0; a < 2; ++a)
#pragma unroll
                for (int r = 0; r < 4; ++r) {
                    float re = accre[a][r], im = accim[a][r];
                    float m2 = fmaf(re, re, im * im);
                    if (PASS == 1) {
                        rm[a][r] = fmaxf(rm[a][r], m2);
                    } else {
                        if (m2 >= thr[a][r]) {
                            int n = row0 + wid * 32 + a * 16 + lhi * 4 + r;
                            int k = col0 + t * TILE_COLS + ch * 16 + l15;
                            int idx = atomicAdd(&cand_cnt, 1);
                            if (idx < CAP) cand[idx] = ((unsigned)n << 14) | (unsigned)k;
                        }
                    }
                }
        }

        if (t + 1 < NTILES) {
            stage_write(1 - cur);
            __syncthreads();
        }
    }
    __syncthreads();

    if (PASS == 1) {
        // reduce max over the 16 col-lanes, then global atomicMax per row
#pragma unroll
        for (int m = 1; m < 16; m <<= 1)
#pragma unroll
            for (int a = 0; a < 2; ++a)
#pragma unroll
                for (int r = 0; r < 4; ++r)
                    rm[a][r] = fmaxf(rm[a][r], __shfl_xor(rm[a][r], m, 64));
        if (l15 == 0) {
#pragma unroll
            for (int a = 0; a < 2; ++a)
#pragma unroll
                for (int r = 0; r < 4; ++r) {
                    int n = row0 + wid * 32 + a * 16 + lhi * 4 + r;
                    atomicMax(&row_max_bits[n], __float_as_uint(rm[a][r]));
                }
        }
    } else {
        // exact fp32 rescore of surviving candidates (round-1 FMA order -> absmax 0)
        int cnt = cand_cnt < CAP ? cand_cnt : CAP;
        for (int i = tid; i < cnt; i += 512) {
            unsigned e = cand[i];
            int n = (int)(e >> 14);
            int k = (int)(e & 16383u);
            const float* xr = x_re + (size_t)n * DD;
            const float* xi = x_im + (size_t)n * DD;
            const float* cr = cb_re + (size_t)k * DD;
            const float* ci = cb_im + (size_t)k * DD;
            float accr = 0.0f, acci = 0.0f;
            for (int d = 0; d < DD; ++d) {
                float xrv = xr[d], xiv = xi[d], crv = cr[d], civ = ci[d];
                accr = fmaf(xrv, crv, accr);
                accr = fmaf(xiv, civ, accr);
                acci = fmaf(xrv, civ, acci);
                acci = fmaf(-xiv, crv, acci);
            }
            float m2 = accr * accr + acci * acci;
            unsigned long long key =
                ((unsigned long long)__float_as_uint(m2) << 32) | (unsigned)(~(unsigned)k);
            atomicMax(&best_packed[n], key);
        }
    }
}

__global__ __launch_bounds__(256) void finalize(
    const unsigned long long* __restrict__ best_packed,
    const float* __restrict__ cb_re, const float* __restrict__ cb_im,
    float* __restrict__ out)
{
    const int wave = threadIdx.x >> 6;
    const int lane = threadIdx.x & 63;
    const int n = blockIdx.x * 4 + wave;
    if (n >= NROWS) return;

    unsigned long long p = best_packed[n];
    unsigned k = ~(unsigned)(p & 0xFFFFFFFFull);

    if (lane == 0) out[n] = (float)k;

    float re = cb_re[(size_t)k * DD + lane];
    float im = cb_im[(size_t)k * DD + lane];
    float2* ro = reinterpret_cast<float2*>(out + NROWS);
    ro[(size_t)n * DD + lane] = make_float2(re, im);
}

extern "C" void kernel_launch(void* const* d_in, const int* in_sizes, int n_in,
                              void* d_out, int out_size, void* d_ws, size_t ws_size,
                              hipStream_t stream)
{
    const float* x_re  = (const float*)d_in[0];
    const float* x_im  = (const float*)d_in[1];
    const float* cb_re = (const float*)d_in[2];
    const float* cb_im = (const float*)d_in[3];
    float* out = (float*)d_out;

    const size_t CB_BYTES = (size_t)KCB * DD * 2;            // 2 MB per array (bf16)
    const size_t NEED = 2 * CB_BYTES + NROWS * 4 + NROWS * 8; // 4.39 MB
    const bool pre = (ws_size >= NEED);

    uint4* cbr_ws; uint4* cbi_ws; unsigned* row_max_bits; unsigned long long* best_packed;
    if (pre) {
        cbr_ws = (uint4*)d_ws;
        cbi_ws = (uint4*)((char*)d_ws + CB_BYTES);
        row_max_bits = (unsigned*)((char*)d_ws + 2 * CB_BYTES);
        best_packed  = (unsigned long long*)((char*)d_ws + 2 * CB_BYTES + NROWS * 4);
    } else {
        cbr_ws = (uint4*)d_ws; cbi_ws = (uint4*)d_ws;          // unused
        row_max_bits = (unsigned*)d_ws;
        best_packed  = (unsigned long long*)((char*)d_ws + NROWS * 4);
    }

    prep<<<pre ? 1024 : (NROWS / 256), 256, 0, stream>>>(
        cb_re, cb_im, cbr_ws, cbi_ws, row_max_bits, best_packed, pre ? 1 : 0);

    dim3 grid(NROWS / BM, CSPLIT);
    if (pre) {
        score_kernel<1, true><<<grid, 512, 0, stream>>>(x_re, x_im, cb_re, cb_im,
            cbr_ws, cbi_ws, row_max_bits, best_packed);
        score_kernel<2, true><<<grid, 512, 0, stream>>>(x_re, x_im, cb_re, cb_im,
            cbr_ws, cbi_ws, row_max_bits, best_packed);
    } else {
        score_kernel<1, false><<<grid, 512, 0, stream>>>(x_re, x_im, cb_re, cb_im,
            cbr_ws, cbi_ws, row_max_bits, best_packed);
        score_kernel<2, false><<<grid, 512, 0, stream>>>(x_re, x_im, cb_re, cb_im,
            cbr_ws, cbi_ws, row_max_bits, best_packed);
    }

    finalize<<<NROWS / 4, 256, 0, stream>>>(best_packed, cb_re, cb_im, out);
}

// Round 5
// 310.625 us; speedup vs baseline: 1.5665x; 1.0812x over previous
//
#include <hip/hip_runtime.h>

#define NROWS 16384
#define KCB   16384
#define DD    64
#define BM    256
#define CSPLIT 16
#define COLS_PER_BLOCK 1024
#define TILE_COLS 128
#define NTILES (COLS_PER_BLOCK / TILE_COLS)   // 8
#define NCHUNK (TILE_COLS / 16)               // 8
#define CAP 2048
#define DELTA 0.45f

typedef __attribute__((ext_vector_type(8))) short bf16x8;
typedef __attribute__((ext_vector_type(4))) float f32x4;

__device__ __forceinline__ unsigned pk_bf16(float lo, float hi) {
    unsigned a = __float_as_uint(lo);
    unsigned b = __float_as_uint(hi);
    a += 0x7FFFu + ((a >> 16) & 1u);   // RNE to bf16
    b += 0x7FFFu + ((b >> 16) & 1u);
    return (a >> 16) | (b & 0xFFFF0000u);
}

__device__ __forceinline__ bf16x8 mk8(unsigned a, unsigned b, unsigned c, unsigned d) {
    union { uint4 u; bf16x8 v; } x;
    x.u = make_uint4(a, b, c, d);
    return x.v;
}

// XOR swizzle within 128B rows: 2-way max aliasing on 16-lane b128 groups (free)
__device__ __forceinline__ unsigned swz(unsigned row, unsigned byte_in_row) {
    return row * 128u + (byte_in_row ^ ((row & 7u) << 4));
}

// prep: zero reductions; optionally convert codebook fp32 -> bf16 (linear [k][64])
__global__ __launch_bounds__(256) void prep(
    const float* __restrict__ cb_re, const float* __restrict__ cb_im,
    uint4* __restrict__ cbr_ws, uint4* __restrict__ cbi_ws,
    unsigned* __restrict__ row_max_bits, unsigned long long* __restrict__ best_packed,
    int do_conv)
{
    int id = blockIdx.x * 256 + threadIdx.x;
    if (id < NROWS) { row_max_bits[id] = 0u; best_packed[id] = 0ull; }
    if (!do_conv) return;
    int row = id >> 4;
    int sub = id & 15;
    const float* src = (sub >> 3) ? cb_im : cb_re;
    uint4* dst = (sub >> 3) ? cbi_ws : cbr_ws;
    int d0 = (sub & 7) * 8;
    const float4* p = (const float4*)(src + (size_t)row * DD + d0);
    float4 f0 = p[0], f1 = p[1];
    dst[row * 8 + (sub & 7)] = make_uint4(
        pk_bf16(f0.x, f0.y), pk_bf16(f0.z, f0.w),
        pk_bf16(f1.x, f1.y), pk_bf16(f1.z, f1.w));
}

template<int PASS, bool PRE>
__global__ __launch_bounds__(512, 2) void score_kernel(
    const float* __restrict__ x_re, const float* __restrict__ x_im,
    const float* __restrict__ cb_re, const float* __restrict__ cb_im,
    const uint4* __restrict__ cbr_ws, const uint4* __restrict__ cbi_ws,
    unsigned* __restrict__ row_max_bits,
    unsigned long long* __restrict__ best_packed)
{
    __shared__ char Bls[2][2][TILE_COLS * 128];   // 64 KB: [buf][re/im][col][d bf16 swz]
    __shared__ unsigned cand[CAP];                // 8 KB
    __shared__ int cand_cnt;

    const int tid  = threadIdx.x;
    const int lane = tid & 63;
    const int wid  = tid >> 6;          // 0..7 = row-group of 32
    const int row0 = blockIdx.x * BM;
    const int col0 = blockIdx.y * COLS_PER_BLOCK;
    const int l15  = lane & 15;
    const int lhi  = lane >> 4;         // 0..3

    if (tid == 0) cand_cnt = 0;

    // ---- A fragments: 32 rows/wave, {re, im, -im}, built once in registers ----
    bf16x8 Ar[2][2], Ai[2][2], Ain[2][2];
#pragma unroll
    for (int a = 0; a < 2; ++a) {
        const int row = row0 + wid * 32 + a * 16 + l15;
#pragma unroll
        for (int ks = 0; ks < 2; ++ks) {
            const float4* pr = (const float4*)(x_re + (size_t)row * DD + ks * 32 + lhi * 8);
            const float4* pi = (const float4*)(x_im + (size_t)row * DD + ks * 32 + lhi * 8);
            float4 r0 = pr[0], r1 = pr[1];
            float4 i0 = pi[0], i1 = pi[1];
            Ar[a][ks] = mk8(pk_bf16(r0.x, r0.y), pk_bf16(r0.z, r0.w),
                            pk_bf16(r1.x, r1.y), pk_bf16(r1.z, r1.w));
            Ai[a][ks] = mk8(pk_bf16(i0.x, i0.y), pk_bf16(i0.z, i0.w),
                            pk_bf16(i1.x, i1.y), pk_bf16(i1.z, i1.w));
            Ain[a][ks] = Ai[a][ks] ^ (short)0x8000;   // exact bf16 negation
        }
    }

    float rm[2][4];
    float thr[2][4];
#pragma unroll
    for (int a = 0; a < 2; ++a)
#pragma unroll
        for (int r = 0; r < 4; ++r) rm[a][r] = 0.0f;
    if (PASS == 2) {
#pragma unroll
        for (int a = 0; a < 2; ++a)
#pragma unroll
            for (int r = 0; r < 4; ++r) {
                int n = row0 + wid * 32 + a * 16 + lhi * 4 + r;
                float mx = __uint_as_float(row_max_bits[n]);
                float tm = sqrtf(mx) - DELTA;
                thr[a][r] = (tm > 0.0f) ? tm * tm : -1.0f;
            }
    }

    // ---- B staging: per tile 128 cols x 128B x {re,im}; thread owns 32B per array ----
    const int scol  = tid >> 2;           // 0..127
    const int sboff = (tid & 3) * 32;     // byte offset within 128B row
    uint4 g[4];                           // in-flight staged regs (16 VGPR)

    auto stage_load = [&](int t) {
        if (PRE) {
            const size_t base = (size_t)(col0 + t * TILE_COLS) * 8 + tid * 2;  // uint4 units
            g[0] = cbr_ws[base];     g[1] = cbr_ws[base + 1];
            g[2] = cbi_ws[base];     g[3] = cbi_ws[base + 1];
        } else {
            const int col = col0 + t * TILE_COLS + scol;
            const int d0  = (tid & 3) * 16;
            const float4* pr = (const float4*)(cb_re + (size_t)col * DD + d0);
            const float4* pi = (const float4*)(cb_im + (size_t)col * DD + d0);
            float4 a0 = pr[0], a1 = pr[1], a2 = pr[2], a3 = pr[3];
            float4 b0 = pi[0], b1 = pi[1], b2 = pi[2], b3 = pi[3];
            g[0] = make_uint4(pk_bf16(a0.x,a0.y), pk_bf16(a0.z,a0.w), pk_bf16(a1.x,a1.y), pk_bf16(a1.z,a1.w));
            g[1] = make_uint4(pk_bf16(a2.x,a2.y), pk_bf16(a2.z,a2.w), pk_bf16(a3.x,a3.y), pk_bf16(a3.z,a3.w));
            g[2] = make_uint4(pk_bf16(b0.x,b0.y), pk_bf16(b0.z,b0.w), pk_bf16(b1.x,b1.y), pk_bf16(b1.z,b1.w));
            g[3] = make_uint4(pk_bf16(b2.x,b2.y), pk_bf16(b2.z,b2.w), pk_bf16(b3.x,b3.y), pk_bf16(b3.z,b3.w));
        }
    };
    auto stage_write = [&](int buf) {
        unsigned o0 = swz(scol, sboff);
        unsigned o1 = swz(scol, sboff + 16);
        *(uint4*)(&Bls[buf][0][0] + o0) = g[0];
        *(uint4*)(&Bls[buf][0][0] + o1) = g[1];
        *(uint4*)(&Bls[buf][1][0] + o0) = g[2];
        *(uint4*)(&Bls[buf][1][0] + o1) = g[3];
    };

    stage_load(0);
    stage_write(0);
    __syncthreads();

    for (int t = 0; t < NTILES; ++t) {
        const int cur = t & 1;
        if (t + 1 < NTILES) stage_load(t + 1);   // HBM/L2 latency hides under MFMA

        const char* B0 = &Bls[cur][0][0];
        const char* B1 = &Bls[cur][1][0];

        for (int ch = 0; ch < NCHUNK; ++ch) {
            const int colLocal = ch * 16 + l15;

            f32x4 accre[2], accim[2];
#pragma unroll
            for (int a = 0; a < 2; ++a) {
                accre[a] = (f32x4){0.f, 0.f, 0.f, 0.f};
                accim[a] = (f32x4){0.f, 0.f, 0.f, 0.f};
            }

#pragma unroll
            for (int ks = 0; ks < 2; ++ks) {
                unsigned off = swz(colLocal, ks * 64 + lhi * 16);
                bf16x8 br = *(const bf16x8*)(B0 + off);
                bf16x8 bi = *(const bf16x8*)(B1 + off);
#pragma unroll
                for (int a = 0; a < 2; ++a)
                    accre[a] = __builtin_amdgcn_mfma_f32_16x16x32_bf16(Ar[a][ks], br, accre[a], 0, 0, 0);
#pragma unroll
                for (int a = 0; a < 2; ++a)
                    accre[a] = __builtin_amdgcn_mfma_f32_16x16x32_bf16(Ai[a][ks], bi, accre[a], 0, 0, 0);
#pragma unroll
                for (int a = 0; a < 2; ++a)
                    accim[a] = __builtin_amdgcn_mfma_f32_16x16x32_bf16(Ar[a][ks], bi, accim[a], 0, 0, 0);
#pragma unroll
                for (int a = 0; a < 2; ++a)
                    accim[a] = __builtin_amdgcn_mfma_f32_16x16x32_bf16(Ain[a][ks], br, accim[a], 0, 0, 0);
            }

#pragma unroll
            for (int a = 0; a < 2; ++a)
#pragma unroll
                for (int r = 0; r < 4; ++r) {
                    float re = accre[a][r], im = accim[a][r];
                    float m2 = fmaf(re, re, im * im);
                    if (PASS == 1) {
                        rm[a][r] = fmaxf(rm[a][r], m2);
                    } else {
                        if (m2 >= thr[a][r]) {
                            int n = row0 + wid * 32 + a * 16 + lhi * 4 + r;
                            int k = col0 + t * TILE_COLS + ch * 16 + l15;
                            int idx = atomicAdd(&cand_cnt, 1);
                            if (idx < CAP) cand[idx] = ((unsigned)n << 14) | (unsigned)k;
                        }
                    }
                }
        }

        if (t + 1 < NTILES) {
            stage_write(1 - cur);
            __syncthreads();
        }
    }
    __syncthreads();

    if (PASS == 1) {
        // reduce max over the 16 col-lanes, then global atomicMax per row
#pragma unroll
        for (int m = 1; m < 16; m <<= 1)
#pragma unroll
            for (int a = 0; a < 2; ++a)
#pragma unroll
                for (int r = 0; r < 4; ++r)
                    rm[a][r] = fmaxf(rm[a][r], __shfl_xor(rm[a][r], m, 64));
        if (l15 == 0) {
#pragma unroll
            for (int a = 0; a < 2; ++a)
#pragma unroll
                for (int r = 0; r < 4; ++r) {
                    int n = row0 + wid * 32 + a * 16 + lhi * 4 + r;
                    atomicMax(&row_max_bits[n], __float_as_uint(rm[a][r]));
                }
        }
    } else {
        // exact fp32 rescore of surviving candidates (round-1 FMA order -> absmax 0)
        int cnt = cand_cnt < CAP ? cand_cnt : CAP;
        for (int i = tid; i < cnt; i += 512) {
            unsigned e = cand[i];
            int n = (int)(e >> 14);
            int k = (int)(e & 16383u);
            const float* xr = x_re + (size_t)n * DD;
            const float* xi = x_im + (size_t)n * DD;
            const float* cr = cb_re + (size_t)k * DD;
            const float* ci = cb_im + (size_t)k * DD;
            float accr = 0.0f, acci = 0.0f;
            for (int d = 0; d < DD; ++d) {
                float xrv = xr[d], xiv = xi[d], crv = cr[d], civ = ci[d];
                accr = fmaf(xrv, crv, accr);
                accr = fmaf(xiv, civ, accr);
                acci = fmaf(xrv, civ, acci);
                acci = fmaf(-xiv, crv, acci);
            }
            float m2 = accr * accr + acci * acci;
            unsigned long long key =
                ((unsigned long long)__float_as_uint(m2) << 32) | (unsigned)(~(unsigned)k);
            atomicMax(&best_packed[n], key);
        }
    }
}

__global__ __launch_bounds__(256) void finalize(
    const unsigned long long* __restrict__ best_packed,
    const float* __restrict__ cb_re, const float* __restrict__ cb_im,
    float* __restrict__ out)
{
    const int wave = threadIdx.x >> 6;
    const int lane = threadIdx.x & 63;
    const int n = blockIdx.x * 4 + wave;
    if (n >= NROWS) return;

    unsigned long long p = best_packed[n];
    unsigned k = ~(unsigned)(p & 0xFFFFFFFFull);

    if (lane == 0) out[n] = (float)k;

    float re = cb_re[(size_t)k * DD + lane];
    float im = cb_im[(size_t)k * DD + lane];
    float2* ro = reinterpret_cast<float2*>(out + NROWS);
    ro[(size_t)n * DD + lane] = make_float2(re, im);
}

extern "C" void kernel_launch(void* const* d_in, const int* in_sizes, int n_in,
                              void* d_out, int out_size, void* d_ws, size_t ws_size,
                              hipStream_t stream)
{
    const float* x_re  = (const float*)d_in[0];
    const float* x_im  = (const float*)d_in[1];
    const float* cb_re = (const float*)d_in[2];
    const float* cb_im = (const float*)d_in[3];
    float* out = (float*)d_out;

    const size_t CB_BYTES = (size_t)KCB * DD * 2;             // 2 MB per array (bf16)
    const size_t NEED = 2 * CB_BYTES + NROWS * 4 + NROWS * 8; // 4.39 MB
    const bool pre = (ws_size >= NEED);

    uint4* cbr_ws; uint4* cbi_ws; unsigned* row_max_bits; unsigned long long* best_packed;
    if (pre) {
        cbr_ws = (uint4*)d_ws;
        cbi_ws = (uint4*)((char*)d_ws + CB_BYTES);
        row_max_bits = (unsigned*)((char*)d_ws + 2 * CB_BYTES);
        best_packed  = (unsigned long long*)((char*)d_ws + 2 * CB_BYTES + NROWS * 4);
    } else {
        cbr_ws = (uint4*)d_ws; cbi_ws = (uint4*)d_ws;          // unused
        row_max_bits = (unsigned*)d_ws;
        best_packed  = (unsigned long long*)((char*)d_ws + NROWS * 4);
    }

    prep<<<pre ? 1024 : (NROWS / 256), 256, 0, stream>>>(
        cb_re, cb_im, cbr_ws, cbi_ws, row_max_bits, best_packed, pre ? 1 : 0);

    dim3 grid(NROWS / BM, CSPLIT);
    if (pre) {
        score_kernel<1, true><<<grid, 512, 0, stream>>>(x_re, x_im, cb_re, cb_im,
            cbr_ws, cbi_ws, row_max_bits, best_packed);
        score_kernel<2, true><<<grid, 512, 0, stream>>>(x_re, x_im, cb_re, cb_im,
            cbr_ws, cbi_ws, row_max_bits, best_packed);
    } else {
        score_kernel<1, false><<<grid, 512, 0, stream>>>(x_re, x_im, cb_re, cb_im,
            cbr_ws, cbi_ws, row_max_bits, best_packed);
        score_kernel<2, false><<<grid, 512, 0, stream>>>(x_re, x_im, cb_re, cb_im,
            cbr_ws, cbi_ws, row_max_bits, best_packed);
    }

    finalize<<<NROWS / 4, 256, 0, stream>>>(best_packed, cb_re, cb_im, out);
}

// Round 6
// 268.655 us; speedup vs baseline: 1.8112x; 1.1562x over previous
//
#include <hip/hip_runtime.h>

#define NROWS 16384
#define KCB   16384
#define DD    64
#define BM    256
#define CSPLIT 16
#define COLS_PER_BLOCK 1024
#define TILE_COLS 128
#define NTILES (COLS_PER_BLOCK / TILE_COLS)   // 8
#define NCHUNK (TILE_COLS / 16)               // 8
#define CAP 2048
#define DELTA 0.45f
#define TILE_BYTES 32768                      // [re 16KB][im 16KB] per 128-col tile

typedef __attribute__((ext_vector_type(8))) short bf16x8;
typedef __attribute__((ext_vector_type(4))) float f32x4;

__device__ __forceinline__ unsigned pk_bf16(float lo, float hi) {
    unsigned a = __float_as_uint(lo);
    unsigned b = __float_as_uint(hi);
    a += 0x7FFFu + ((a >> 16) & 1u);   // RNE to bf16
    b += 0x7FFFu + ((b >> 16) & 1u);
    return (a >> 16) | (b & 0xFFFF0000u);
}

__device__ __forceinline__ bf16x8 mk8(unsigned a, unsigned b, unsigned c, unsigned d) {
    union { uint4 u; bf16x8 v; } x;
    x.u = make_uint4(a, b, c, d);
    return x.v;
}

// XOR swizzle within 128B rows: 16 lanes -> 8 bank-slots = 2-way (free)
__device__ __forceinline__ unsigned swz(unsigned row, unsigned byte_in_row) {
    return row * 128u + (byte_in_row ^ ((row & 7u) << 4));
}

__device__ __forceinline__ void gload_lds16(const void* g, void* l) {
    __builtin_amdgcn_global_load_lds(
        (__attribute__((address_space(1))) void*)(g),
        (__attribute__((address_space(3))) void*)(l), 16, 0, 0);
}

// prep: zero reductions; convert codebook fp32 -> bf16 in INVERSE-SWIZZLED
// tile order so that linear global_load_lds writes produce the swizzled LDS
// layout the compute phase reads (rule #21: permute source, read swizzled).
__global__ __launch_bounds__(256) void prep(
    const float* __restrict__ cb_re, const float* __restrict__ cb_im,
    uint4* __restrict__ cb_sw,
    unsigned* __restrict__ row_max_bits, unsigned long long* __restrict__ best_packed,
    int do_conv)
{
    int id = blockIdx.x * 256 + threadIdx.x;
    if (id < NROWS) { row_max_bits[id] = 0u; best_packed[id] = 0ull; }
    if (!do_conv) return;
    // id in [0, 262144): [gt 0..127][arr 0..1][u 0..1023], one uint4 (16B) each
    int u   = id & 1023;
    int arr = (id >> 10) & 1;
    int gt  = id >> 11;
    int c   = u >> 3;                                  // col within tile
    int b   = ((u & 7) * 16) ^ ((c & 7) << 4);         // inverse-swizzled byte
    int col = gt * TILE_COLS + c;
    int d0  = b >> 1;                                  // bf16 element index (8-aligned)
    const float* src = arr ? cb_im : cb_re;
    const float4* p = (const float4*)(src + (size_t)col * DD + d0);
    float4 f0 = p[0], f1 = p[1];
    cb_sw[id] = make_uint4(pk_bf16(f0.x, f0.y), pk_bf16(f0.z, f0.w),
                           pk_bf16(f1.x, f1.y), pk_bf16(f1.z, f1.w));
}

template<int PASS, bool PRE>
__global__ __launch_bounds__(512, 2) void score_kernel(
    const float* __restrict__ x_re, const float* __restrict__ x_im,
    const float* __restrict__ cb_re, const float* __restrict__ cb_im,
    const char* __restrict__ cb_sw,
    unsigned* __restrict__ row_max_bits,
    unsigned long long* __restrict__ best_packed)
{
    __shared__ char Bls[2][2][TILE_COLS * 128];   // 64 KB: [buf][re/im][16KB swizzled]
    __shared__ unsigned cand[CAP];                // 8 KB
    __shared__ int cand_cnt;

    const int tid  = threadIdx.x;
    const int lane = tid & 63;
    const int wid  = tid >> 6;          // 0..7 = row-group of 32
    const int row0 = blockIdx.x * BM;
    const int col0 = blockIdx.y * COLS_PER_BLOCK;
    const int l15  = lane & 15;
    const int lhi  = lane >> 4;         // 0..3

    if (tid == 0) cand_cnt = 0;

    // ---- A fragments: 32 rows/wave, {re, im}, literal-index access only ----
    bf16x8 Ar[2][2], Ai[2][2];
#pragma unroll
    for (int a = 0; a < 2; ++a) {
        const int row = row0 + wid * 32 + a * 16 + l15;
        {
            const float4* pr = (const float4*)(x_re + (size_t)row * DD + lhi * 8);
            const float4* pi = (const float4*)(x_im + (size_t)row * DD + lhi * 8);
            float4 r0 = pr[0], r1 = pr[1];
            float4 i0 = pi[0], i1 = pi[1];
            Ar[a][0] = mk8(pk_bf16(r0.x, r0.y), pk_bf16(r0.z, r0.w),
                           pk_bf16(r1.x, r1.y), pk_bf16(r1.z, r1.w));
            Ai[a][0] = mk8(pk_bf16(i0.x, i0.y), pk_bf16(i0.z, i0.w),
                           pk_bf16(i1.x, i1.y), pk_bf16(i1.z, i1.w));
        }
        {
            const float4* pr = (const float4*)(x_re + (size_t)row * DD + 32 + lhi * 8);
            const float4* pi = (const float4*)(x_im + (size_t)row * DD + 32 + lhi * 8);
            float4 r0 = pr[0], r1 = pr[1];
            float4 i0 = pi[0], i1 = pi[1];
            Ar[a][1] = mk8(pk_bf16(r0.x, r0.y), pk_bf16(r0.z, r0.w),
                           pk_bf16(r1.x, r1.y), pk_bf16(r1.z, r1.w));
            Ai[a][1] = mk8(pk_bf16(i0.x, i0.y), pk_bf16(i0.z, i0.w),
                           pk_bf16(i1.x, i1.y), pk_bf16(i1.z, i1.w));
        }
    }

    float rm[2][4];
    float thr[2][4];
#pragma unroll
    for (int a = 0; a < 2; ++a)
#pragma unroll
        for (int r = 0; r < 4; ++r) rm[a][r] = 0.0f;
    if (PASS == 2) {
#pragma unroll
        for (int a = 0; a < 2; ++a)
#pragma unroll
            for (int r = 0; r < 4; ++r) {
                int n = row0 + wid * 32 + a * 16 + lhi * 4 + r;
                float mx = __uint_as_float(row_max_bits[n]);
                float tm = sqrtf(mx) - DELTA;
                thr[a][r] = (tm > 0.0f) ? tm * tm : -1.0f;
            }
    }

    // ================= compute macro (shared by both paths) =================
#define CHUNK_BODY(T_IDX, CH)                                                   \
    {                                                                           \
        const char* B0 = &Bls[(T_IDX) & 1][0][0];                               \
        const char* B1 = &Bls[(T_IDX) & 1][1][0];                               \
        const int colLocal = (CH) * 16 + l15;                                   \
        unsigned off0 = swz(colLocal, lhi * 16);                                \
        unsigned off1 = swz(colLocal, 64 + lhi * 16);                           \
        bf16x8 br0 = *(const bf16x8*)(B0 + off0);                               \
        bf16x8 bi0 = *(const bf16x8*)(B1 + off0);                               \
        bf16x8 br1 = *(const bf16x8*)(B0 + off1);                               \
        bf16x8 bi1 = *(const bf16x8*)(B1 + off1);                               \
        f32x4 accre[2], accim[2];                                               \
        _Pragma("unroll")                                                       \
        for (int a = 0; a < 2; ++a) {                                           \
            accre[a] = (f32x4){0.f, 0.f, 0.f, 0.f};                             \
            accim[a] = (f32x4){0.f, 0.f, 0.f, 0.f};                             \
        }                                                                       \
        _Pragma("unroll")                                                       \
        for (int a = 0; a < 2; ++a) {                                           \
            accre[a] = __builtin_amdgcn_mfma_f32_16x16x32_bf16(Ar[a][0], br0, accre[a], 0, 0, 0); \
            accre[a] = __builtin_amdgcn_mfma_f32_16x16x32_bf16(Ai[a][0], bi0, accre[a], 0, 0, 0); \
            accre[a] = __builtin_amdgcn_mfma_f32_16x16x32_bf16(Ar[a][1], br1, accre[a], 0, 0, 0); \
            accre[a] = __builtin_amdgcn_mfma_f32_16x16x32_bf16(Ai[a][1], bi1, accre[a], 0, 0, 0); \
            accim[a] = __builtin_amdgcn_mfma_f32_16x16x32_bf16(Ar[a][0], bi0, accim[a], 0, 0, 0); \
            accim[a] = __builtin_amdgcn_mfma_f32_16x16x32_bf16(Ar[a][1], bi1, accim[a], 0, 0, 0); \
        }                                                                       \
        br0 = br0 ^ (short)0x8000;                                              \
        br1 = br1 ^ (short)0x8000;                                              \
        _Pragma("unroll")                                                       \
        for (int a = 0; a < 2; ++a) {                                           \
            accim[a] = __builtin_amdgcn_mfma_f32_16x16x32_bf16(Ai[a][0], br0, accim[a], 0, 0, 0); \
            accim[a] = __builtin_amdgcn_mfma_f32_16x16x32_bf16(Ai[a][1], br1, accim[a], 0, 0, 0); \
        }                                                                       \
        _Pragma("unroll")                                                       \
        for (int a = 0; a < 2; ++a)                                             \
            _Pragma("unroll")                                                   \
            for (int r = 0; r < 4; ++r) {                                       \
                float re = accre[a][r], im = accim[a][r];                       \
                float m2 = fmaf(re, re, im * im);                               \
                if (PASS == 1) {                                                \
                    rm[a][r] = fmaxf(rm[a][r], m2);                             \
                } else {                                                        \
                    if (m2 >= thr[a][r]) {                                      \
                        int n = row0 + wid * 32 + a * 16 + lhi * 4 + r;         \
                        int k = col0 + (T_IDX) * TILE_COLS + (CH) * 16 + l15;   \
                        int idx = atomicAdd(&cand_cnt, 1);                      \
                        if (idx < CAP) cand[idx] = ((unsigned)n << 14) | (unsigned)k; \
                    }                                                           \
                }                                                               \
            }                                                                   \
    }

    if constexpr (PRE) {
        // ---- global_load_lds pipeline: pre-swizzled source, linear LDS dest ----
        const char* tile_base = cb_sw + (size_t)blockIdx.y * NTILES * TILE_BYTES;
        auto stage = [&](int buf, int t) {
            const char* src = tile_base + (size_t)t * TILE_BYTES;
            char* dst = &Bls[buf][0][0];
#pragma unroll
            for (int j = 0; j < 4; ++j)
                gload_lds16(src + j * 8192 + tid * 16, dst + j * 8192 + tid * 16);
        };

        stage(0, 0);
        __syncthreads();   // drain tile-0 loads + make cand_cnt=0 visible

        for (int t = 0; t < NTILES; ++t) {
            const int cur = t & 1;
            if (t + 1 < NTILES) {
                stage(cur ^ 1, t + 1);                         // 4 loads in flight
                asm volatile("s_waitcnt vmcnt(4)" ::: "memory");  // tile t done; t+1 stays in flight
            } else {
                asm volatile("s_waitcnt vmcnt(0)" ::: "memory");
            }
            __builtin_amdgcn_sched_barrier(0);
            __builtin_amdgcn_s_barrier();
            __builtin_amdgcn_sched_barrier(0);

            for (int ch = 0; ch < NCHUNK; ++ch)
                CHUNK_BODY(t, ch)

            __builtin_amdgcn_sched_barrier(0);
            __builtin_amdgcn_s_barrier();   // all waves done reading buf before overwrite
        }
        __syncthreads();
    } else {
        // ---- fallback: reg-staged (r5 structure) ----
        const int scol  = tid >> 2;
        const int sboff = (tid & 3) * 32;
        uint4 g[4];
        auto stage_load = [&](int t) {
            const int col = col0 + t * TILE_COLS + scol;
            const int d0  = (tid & 3) * 16;
            const float4* pr = (const float4*)(cb_re + (size_t)col * DD + d0);
            const float4* pi = (const float4*)(cb_im + (size_t)col * DD + d0);
            float4 a0 = pr[0], a1 = pr[1], a2 = pr[2], a3 = pr[3];
            float4 b0 = pi[0], b1 = pi[1], b2 = pi[2], b3 = pi[3];
            g[0] = make_uint4(pk_bf16(a0.x,a0.y), pk_bf16(a0.z,a0.w), pk_bf16(a1.x,a1.y), pk_bf16(a1.z,a1.w));
            g[1] = make_uint4(pk_bf16(a2.x,a2.y), pk_bf16(a2.z,a2.w), pk_bf16(a3.x,a3.y), pk_bf16(a3.z,a3.w));
            g[2] = make_uint4(pk_bf16(b0.x,b0.y), pk_bf16(b0.z,b0.w), pk_bf16(b1.x,b1.y), pk_bf16(b1.z,b1.w));
            g[3] = make_uint4(pk_bf16(b2.x,b2.y), pk_bf16(b2.z,b2.w), pk_bf16(b3.x,b3.y), pk_bf16(b3.z,b3.w));
        };
        auto stage_write = [&](int buf) {
            unsigned o0 = swz(scol, sboff);
            unsigned o1 = swz(scol, sboff + 16);
            *(uint4*)(&Bls[buf][0][0] + o0) = g[0];
            *(uint4*)(&Bls[buf][0][0] + o1) = g[1];
            *(uint4*)(&Bls[buf][1][0] + o0) = g[2];
            *(uint4*)(&Bls[buf][1][0] + o1) = g[3];
        };
        stage_load(0);
        stage_write(0);
        __syncthreads();
        for (int t = 0; t < NTILES; ++t) {
            if (t + 1 < NTILES) stage_load(t + 1);
            for (int ch = 0; ch < NCHUNK; ++ch)
                CHUNK_BODY(t, ch)
            if (t + 1 < NTILES) {
                stage_write(1 - (t & 1));
                __syncthreads();
            }
        }
        __syncthreads();
    }
#undef CHUNK_BODY

    if (PASS == 1) {
        // reduce max over the 16 col-lanes, then global atomicMax per row
#pragma unroll
        for (int m = 1; m < 16; m <<= 1)
#pragma unroll
            for (int a = 0; a < 2; ++a)
#pragma unroll
                for (int r = 0; r < 4; ++r)
                    rm[a][r] = fmaxf(rm[a][r], __shfl_xor(rm[a][r], m, 64));
        if (l15 == 0) {
#pragma unroll
            for (int a = 0; a < 2; ++a)
#pragma unroll
                for (int r = 0; r < 4; ++r) {
                    int n = row0 + wid * 32 + a * 16 + lhi * 4 + r;
                    atomicMax(&row_max_bits[n], __float_as_uint(rm[a][r]));
                }
        }
    } else {
        // exact fp32 rescore of surviving candidates (round-1 FMA order -> absmax 0)
        int cnt = cand_cnt < CAP ? cand_cnt : CAP;
        for (int i = tid; i < cnt; i += 512) {
            unsigned e = cand[i];
            int n = (int)(e >> 14);
            int k = (int)(e & 16383u);
            const float* xr = x_re + (size_t)n * DD;
            const float* xi = x_im + (size_t)n * DD;
            const float* cr = cb_re + (size_t)k * DD;
            const float* ci = cb_im + (size_t)k * DD;
            float accr = 0.0f, acci = 0.0f;
            for (int d = 0; d < DD; ++d) {
                float xrv = xr[d], xiv = xi[d], crv = cr[d], civ = ci[d];
                accr = fmaf(xrv, crv, accr);
                accr = fmaf(xiv, civ, accr);
                acci = fmaf(xrv, civ, acci);
                acci = fmaf(-xiv, crv, acci);
            }
            float m2 = accr * accr + acci * acci;
            unsigned long long key =
                ((unsigned long long)__float_as_uint(m2) << 32) | (unsigned)(~(unsigned)k);
            atomicMax(&best_packed[n], key);
        }
    }
}

__global__ __launch_bounds__(256) void finalize(
    const unsigned long long* __restrict__ best_packed,
    const float* __restrict__ cb_re, const float* __restrict__ cb_im,
    float* __restrict__ out)
{
    const int wave = threadIdx.x >> 6;
    const int lane = threadIdx.x & 63;
    const int n = blockIdx.x * 4 + wave;
    if (n >= NROWS) return;

    unsigned long long p = best_packed[n];
    unsigned k = ~(unsigned)(p & 0xFFFFFFFFull);

    if (lane == 0) out[n] = (float)k;

    float re = cb_re[(size_t)k * DD + lane];
    float im = cb_im[(size_t)k * DD + lane];
    float2* ro = reinterpret_cast<float2*>(out + NROWS);
    ro[(size_t)n * DD + lane] = make_float2(re, im);
}

extern "C" void kernel_launch(void* const* d_in, const int* in_sizes, int n_in,
                              void* d_out, int out_size, void* d_ws, size_t ws_size,
                              hipStream_t stream)
{
    const float* x_re  = (const float*)d_in[0];
    const float* x_im  = (const float*)d_in[1];
    const float* cb_re = (const float*)d_in[2];
    const float* cb_im = (const float*)d_in[3];
    float* out = (float*)d_out;

    const size_t CB_SW_BYTES = (size_t)(KCB / TILE_COLS) * TILE_BYTES;   // 4 MB
    const size_t NEED = CB_SW_BYTES + NROWS * 4 + NROWS * 8;             // ~4.4 MB
    const bool pre = (ws_size >= NEED);

    const char* cb_sw = (const char*)d_ws;
    unsigned* row_max_bits;
    unsigned long long* best_packed;
    if (pre) {
        row_max_bits = (unsigned*)((char*)d_ws + CB_SW_BYTES);
        best_packed  = (unsigned long long*)((char*)d_ws + CB_SW_BYTES + NROWS * 4);
    } else {
        row_max_bits = (unsigned*)d_ws;
        best_packed  = (unsigned long long*)((char*)d_ws + NROWS * 4);
    }

    prep<<<pre ? 1024 : (NROWS / 256), 256, 0, stream>>>(
        cb_re, cb_im, (uint4*)d_ws, row_max_bits, best_packed, pre ? 1 : 0);

    dim3 grid(NROWS / BM, CSPLIT);
    if (pre) {
        score_kernel<1, true><<<grid, 512, 0, stream>>>(x_re, x_im, cb_re, cb_im,
            cb_sw, row_max_bits, best_packed);
        score_kernel<2, true><<<grid, 512, 0, stream>>>(x_re, x_im, cb_re, cb_im,
            cb_sw, row_max_bits, best_packed);
    } else {
        score_kernel<1, false><<<grid, 512, 0, stream>>>(x_re, x_im, cb_re, cb_im,
            cb_sw, row_max_bits, best_packed);
        score_kernel<2, false><<<grid, 512, 0, stream>>>(x_re, x_im, cb_re, cb_im,
            cb_sw, row_max_bits, best_packed);
    }

    finalize<<<NROWS / 4, 256, 0, stream>>>(best_packed, cb_re, cb_im, out);
}